// Round 1
// baseline (283.620 us; speedup 1.0000x reference)
//
#include <hip/hip_runtime.h>
#include <hip/hip_bf16.h>

#define QMAX 255.0f

// ws float-offset layout
#define OFF_QW1 16
#define OFF_QW2 466       // 16+450
#define OFF_QW3 2866      // +2400
#define OFF_QW4 50866     // +48000
#define OFF_QW5 60946     // +10080
#define OFF_H1  61952     // aligned
#define OFF_H2  (OFF_H1 + 4096*6*14*14)
#define OFF_H3  (OFF_H2 + 4096*16*5*5)
#define OFF_H4  (OFF_H3 + 4096*120)

__device__ __forceinline__ float get_scale(const unsigned* slots, int i) {
    float amax = __uint_as_float(slots[i]);
    float s = amax / QMAX;
    if (!(s > 0.0f)) s = 1.0f;
    return s;
}

// ---------------- weight prep: per-weight absmax + quantize (5 blocks) ----------------
__global__ __launch_bounds__(256) void k_prep_w(
    const float* __restrict__ w1, const float* __restrict__ w2,
    const float* __restrict__ w3, const float* __restrict__ w4,
    const float* __restrict__ w5,
    unsigned* __restrict__ slots,
    float* __restrict__ qw1, float* __restrict__ qw2, float* __restrict__ qw3,
    float* __restrict__ qw4, float* __restrict__ qw5)
{
    __shared__ float red[256];
    int b = blockIdx.x, tid = threadIdx.x;
    if (b == 0 && tid < 5) slots[tid] = 0u;   // init activation absmax slots 0..4
    const float* w; float* q; int n;
    if      (b == 0) { w = w1; q = qw1; n = 450;   }
    else if (b == 1) { w = w2; q = qw2; n = 2400;  }
    else if (b == 2) { w = w3; q = qw3; n = 48000; }
    else if (b == 3) { w = w4; q = qw4; n = 10080; }
    else             { w = w5; q = qw5; n = 840;   }
    float m = 0.0f;
    for (int i = tid; i < n; i += 256) m = fmaxf(m, fabsf(w[i]));
    red[tid] = m; __syncthreads();
    for (int s = 128; s > 0; s >>= 1) {
        if (tid < s) red[tid] = fmaxf(red[tid], red[tid + s]);
        __syncthreads();
    }
    float amax = red[0];
    if (tid == 0) slots[5 + b] = __float_as_uint(amax);
    float s = amax / QMAX; if (!(s > 0.0f)) s = 1.0f;
    for (int i = tid; i < n; i += 256) q[i] = rintf(w[i] / s);
}

// ---------------- absmax over x ----------------
__global__ __launch_bounds__(256) void k_absmax_x(
    const float4* __restrict__ x, int n4, unsigned* __restrict__ slot)
{
    __shared__ float red[256];
    int tid = threadIdx.x;
    float m = 0.0f;
    for (int i = blockIdx.x * blockDim.x + tid; i < n4; i += gridDim.x * blockDim.x) {
        float4 v = x[i];
        m = fmaxf(m, fmaxf(fmaxf(fabsf(v.x), fabsf(v.y)), fmaxf(fabsf(v.z), fabsf(v.w))));
    }
    red[tid] = m; __syncthreads();
    for (int s = 128; s > 0; s >>= 1) {
        if (tid < s) red[tid] = fmaxf(red[tid], red[tid + s]);
        __syncthreads();
    }
    if (tid == 0) atomicMax(slot, __float_as_uint(red[0]));
}

// ---------------- conv1 + relu + pool: [B,3,32,32] -> [B,6,14,14] ----------------
__global__ __launch_bounds__(256) void k_conv1(
    const float* __restrict__ x, const float* __restrict__ qw1,
    const unsigned* __restrict__ slots, unsigned* __restrict__ slot_out,
    float* __restrict__ h1)
{
    __shared__ float xs[3 * 32 * 32];
    __shared__ float red[256];
    int b = blockIdx.x, tid = threadIdx.x;
    float sx = get_scale(slots, 0);
    const float* xb = x + (long)b * 3072;
    for (int i = tid; i < 3072; i += 256) xs[i] = rintf(xb[i] / sx);
    __syncthreads();
    float mscale = sx * get_scale(slots, 5);

    float vmax = 0.0f;
    if (tid < 196) {
        int py = tid / 14, px = tid % 14;
        float acc[6][4];
        #pragma unroll
        for (int oc = 0; oc < 6; oc++)
            #pragma unroll
            for (int p = 0; p < 4; p++) acc[oc][p] = 0.0f;

        for (int c = 0; c < 3; c++) {
            float xw[6][6];
            #pragma unroll
            for (int r = 0; r < 6; r++)
                #pragma unroll
                for (int cc = 0; cc < 6; cc++)
                    xw[r][cc] = xs[c * 1024 + (2 * py + r) * 32 + (2 * px + cc)];
            #pragma unroll
            for (int oc = 0; oc < 6; oc++) {
                #pragma unroll
                for (int ky = 0; ky < 5; ky++)
                    #pragma unroll
                    for (int kx = 0; kx < 5; kx++) {
                        float w = qw1[((oc * 3 + c) * 5 + ky) * 5 + kx];
                        acc[oc][0] += xw[ky][kx]     * w;
                        acc[oc][1] += xw[ky][kx + 1] * w;
                        acc[oc][2] += xw[ky + 1][kx] * w;
                        acc[oc][3] += xw[ky + 1][kx + 1] * w;
                    }
            }
        }
        #pragma unroll
        for (int oc = 0; oc < 6; oc++) {
            float m = fmaxf(fmaxf(acc[oc][0], acc[oc][1]), fmaxf(acc[oc][2], acc[oc][3]));
            float v = fmaxf(m * mscale, 0.0f);
            h1[((long)b * 6 + oc) * 196 + tid] = v;
            vmax = fmaxf(vmax, v);
        }
    }
    red[tid] = vmax; __syncthreads();
    for (int s = 128; s > 0; s >>= 1) {
        if (tid < s) red[tid] = fmaxf(red[tid], red[tid + s]);
        __syncthreads();
    }
    if (tid == 0) atomicMax(slot_out, __float_as_uint(red[0]));
}

// ---------------- conv2 + relu + pool: [B,6,14,14] -> [B,16,5,5] (8 img/block) ----------------
__global__ __launch_bounds__(256) void k_conv2(
    const float* __restrict__ h1, const float* __restrict__ qw2,
    const unsigned* __restrict__ slots, unsigned* __restrict__ slot_out,
    float* __restrict__ h2)
{
    __shared__ float xs[8 * 6 * 196];
    __shared__ float red[256];
    int b0 = blockIdx.x * 8, tid = threadIdx.x;
    float s1 = get_scale(slots, 1);
    const float* src = h1 + (long)b0 * 1176;
    for (int i = tid; i < 8 * 1176; i += 256) xs[i] = rintf(src[i] / s1);
    __syncthreads();
    float mscale = s1 * get_scale(slots, 6);

    float vmax = 0.0f;
    if (tid < 200) {
        int img = tid / 25, p = tid % 25;
        int py = p / 5, px = p % 5;
        int xbase = img * 1176;
        for (int ocg = 0; ocg < 2; ocg++) {
            float acc[8][4];
            #pragma unroll
            for (int oc = 0; oc < 8; oc++)
                #pragma unroll
                for (int q = 0; q < 4; q++) acc[oc][q] = 0.0f;

            for (int c = 0; c < 6; c++) {
                float xw[6][6];
                #pragma unroll
                for (int r = 0; r < 6; r++)
                    #pragma unroll
                    for (int cc = 0; cc < 6; cc++)
                        xw[r][cc] = xs[xbase + c * 196 + (2 * py + r) * 14 + (2 * px + cc)];
                #pragma unroll
                for (int oc = 0; oc < 8; oc++) {
                    #pragma unroll
                    for (int ky = 0; ky < 5; ky++)
                        #pragma unroll
                        for (int kx = 0; kx < 5; kx++) {
                            float w = qw2[(((ocg * 8 + oc) * 6 + c) * 5 + ky) * 5 + kx];
                            acc[oc][0] += xw[ky][kx]     * w;
                            acc[oc][1] += xw[ky][kx + 1] * w;
                            acc[oc][2] += xw[ky + 1][kx] * w;
                            acc[oc][3] += xw[ky + 1][kx + 1] * w;
                        }
                }
            }
            #pragma unroll
            for (int oc = 0; oc < 8; oc++) {
                float m = fmaxf(fmaxf(acc[oc][0], acc[oc][1]), fmaxf(acc[oc][2], acc[oc][3]));
                float v = fmaxf(m * mscale, 0.0f);
                h2[((long)(b0 + img) * 16 + ocg * 8 + oc) * 25 + p] = v;
                vmax = fmaxf(vmax, v);
            }
        }
    }
    red[tid] = vmax; __syncthreads();
    for (int s = 128; s > 0; s >>= 1) {
        if (tid < s) red[tid] = fmaxf(red[tid], red[tid + s]);
        __syncthreads();
    }
    if (tid == 0) atomicMax(slot_out, __float_as_uint(red[0]));
}

// ---------------- conv3 + relu: [B,16,5,5] -> [B,120]  (GEMM M=B,N=120,K=400; 16 img/block) ----------------
__global__ __launch_bounds__(256) void k_conv3(
    const float* __restrict__ h2, const float* __restrict__ qw3,
    const unsigned* __restrict__ slots, unsigned* __restrict__ slot_out,
    float* __restrict__ h3)
{
    __shared__ float xs[16 * 401];
    __shared__ float wt[50 * 120];
    __shared__ float red[256];
    int b0 = blockIdx.x * 16, tid = threadIdx.x;
    float s2 = get_scale(slots, 2);
    const float* src = h2 + (long)b0 * 400;
    for (int i = tid; i < 6400; i += 256) {
        int img = i / 400, k = i % 400;
        xs[img * 401 + k] = rintf(src[i] / s2);
    }
    float mscale = s2 * get_scale(slots, 7);
    int img = tid & 15, ocg = tid >> 4;
    int ocb = ocg * 8;
    float acc[8];
    #pragma unroll
    for (int j = 0; j < 8; j++) acc[j] = 0.0f;

    for (int cc = 0; cc < 8; cc++) {
        __syncthreads();
        for (int i = tid; i < 6000; i += 256) {
            int oc = i / 50, kk = i % 50;
            wt[kk * 120 + oc] = qw3[oc * 400 + cc * 50 + kk];
        }
        __syncthreads();
        if (ocg < 15) {
            for (int kk = 0; kk < 50; kk++) {
                float xv = xs[img * 401 + cc * 50 + kk];
                const float* wr = &wt[kk * 120 + ocb];
                #pragma unroll
                for (int j = 0; j < 8; j++) acc[j] += xv * wr[j];
            }
        }
    }
    float vmax = 0.0f;
    if (ocg < 15) {
        #pragma unroll
        for (int j = 0; j < 8; j++) {
            float v = fmaxf(acc[j] * mscale, 0.0f);
            h3[(long)(b0 + img) * 120 + ocb + j] = v;
            vmax = fmaxf(vmax, v);
        }
    }
    red[tid] = vmax; __syncthreads();
    for (int s = 128; s > 0; s >>= 1) {
        if (tid < s) red[tid] = fmaxf(red[tid], red[tid + s]);
        __syncthreads();
    }
    if (tid == 0) atomicMax(slot_out, __float_as_uint(red[0]));
}

// ---------------- fc4 + relu: [B,120] x [84,120] -> [B,84]  (16 img/block) ----------------
__global__ __launch_bounds__(256) void k_fc4(
    const float* __restrict__ h3, const float* __restrict__ qw4,
    const unsigned* __restrict__ slots, unsigned* __restrict__ slot_out,
    float* __restrict__ h4)
{
    __shared__ float xs[16 * 121];
    __shared__ float wt[120 * 84];
    __shared__ float red[256];
    int b0 = blockIdx.x * 16, tid = threadIdx.x;
    float s3 = get_scale(slots, 3);
    const float* src = h3 + (long)b0 * 120;
    for (int i = tid; i < 1920; i += 256) {
        int img = i / 120, k = i % 120;
        xs[img * 121 + k] = rintf(src[i] / s3);
    }
    for (int i = tid; i < 10080; i += 256) {
        int oc = i / 120, k = i % 120;
        wt[k * 84 + oc] = qw4[i];
    }
    __syncthreads();
    float mscale = s3 * get_scale(slots, 8);
    int img = tid & 15, ocg = tid >> 4;
    int ocb = ocg * 6;
    float vmax = 0.0f;
    if (ocg < 14) {
        float acc[6];
        #pragma unroll
        for (int j = 0; j < 6; j++) acc[j] = 0.0f;
        for (int k = 0; k < 120; k++) {
            float xv = xs[img * 121 + k];
            const float* wr = &wt[k * 84 + ocb];
            #pragma unroll
            for (int j = 0; j < 6; j++) acc[j] += xv * wr[j];
        }
        #pragma unroll
        for (int j = 0; j < 6; j++) {
            float v = fmaxf(acc[j] * mscale, 0.0f);
            h4[(long)(b0 + img) * 84 + ocb + j] = v;
            vmax = fmaxf(vmax, v);
        }
    }
    red[tid] = vmax; __syncthreads();
    for (int s = 128; s > 0; s >>= 1) {
        if (tid < s) red[tid] = fmaxf(red[tid], red[tid + s]);
        __syncthreads();
    }
    if (tid == 0) atomicMax(slot_out, __float_as_uint(red[0]));
}

// ---------------- fc5: [B,84] x [10,84] -> out [B,10] ----------------
__global__ __launch_bounds__(256) void k_fc5(
    const float* __restrict__ h4, const float* __restrict__ qw5,
    const unsigned* __restrict__ slots, float* __restrict__ out)
{
    __shared__ float wt[840];
    int tid = threadIdx.x;
    int gid = blockIdx.x * 256 + tid;
    float s4 = get_scale(slots, 4);
    for (int i = tid; i < 840; i += 256) wt[i] = qw5[i];
    __syncthreads();
    float mscale = s4 * get_scale(slots, 9);
    int img = gid / 10, oc = gid % 10;
    if (img < 4096) {
        float acc = 0.0f;
        const float* xr = h4 + (long)img * 84;
        const float* wr = &wt[oc * 84];
        for (int k = 0; k < 84; k++) acc += rintf(xr[k] / s4) * wr[k];
        out[gid] = acc * mscale;
    }
}

extern "C" void kernel_launch(void* const* d_in, const int* in_sizes, int n_in,
                              void* d_out, int out_size, void* d_ws, size_t ws_size,
                              hipStream_t stream) {
    const float* x  = (const float*)d_in[0];
    const float* w1 = (const float*)d_in[1];
    const float* w2 = (const float*)d_in[2];
    const float* w3 = (const float*)d_in[3];
    const float* w4 = (const float*)d_in[4];
    const float* w5 = (const float*)d_in[5];
    float* out = (float*)d_out;
    float* ws = (float*)d_ws;
    unsigned* slots = (unsigned*)d_ws;
    float* qw1 = ws + OFF_QW1;
    float* qw2 = ws + OFF_QW2;
    float* qw3 = ws + OFF_QW3;
    float* qw4 = ws + OFF_QW4;
    float* qw5 = ws + OFF_QW5;
    float* h1 = ws + OFF_H1;
    float* h2 = ws + OFF_H2;
    float* h3 = ws + OFF_H3;
    float* h4 = ws + OFF_H4;

    k_prep_w<<<5, 256, 0, stream>>>(w1, w2, w3, w4, w5, slots, qw1, qw2, qw3, qw4, qw5);
    k_absmax_x<<<2048, 256, 0, stream>>>((const float4*)x, 4096 * 3 * 32 * 32 / 4, slots + 0);
    k_conv1<<<4096, 256, 0, stream>>>(x, qw1, slots, slots + 1, h1);
    k_conv2<<<512, 256, 0, stream>>>(h1, qw2, slots, slots + 2, h2);
    k_conv3<<<256, 256, 0, stream>>>(h2, qw3, slots, slots + 3, h3);
    k_fc4<<<256, 256, 0, stream>>>(h3, qw4, slots, slots + 4, h4);
    k_fc5<<<160, 256, 0, stream>>>(h4, qw5, slots, out);
}